// Round 1
// baseline (270.248 us; speedup 1.0000x reference)
//
#include <hip/hip_runtime.h>
#include <math.h>

#define D  32
#define BN 16384
#define PP 16

typedef __bf16 bf16x8 __attribute__((ext_vector_type(8)));
typedef __bf16 bf16x4 __attribute__((ext_vector_type(4)));
typedef float  floatx4 __attribute__((ext_vector_type(4)));

#define K1 1.44269504088896341f      // log2(e)
#define K2 2.88539008177792681f      // 2*log2(e)

// LDS image: only the MFMA A-operands now.
//   Wu  = Wih[:,0:32] bf16 [gate][stride 40]  (80 B rows -> banks 20*gate)
//   Whh = bf16 [gate][stride 40]
// acc-init comes from GLOBAL combined tables (f32, L2/L3-resident):
//   T0[hop][k][g]    = bias[g] + Wih[g][32:64]@ent[k]          (step 0)
//   T [hop][j][k][g] = bias[g] + Wih[g][0:32]@rel[j]
//                              + Wih[g][32:64]@ent[k]          (steps >=1)
#define WU_OFF     0
#define WHH_OFF    10240
#define WIMG_BYTES 20480
#define H_OFF      20480
#define LDS_BYTES  (WIMG_BYTES + 8 * 1280)   // + H: 4 waves x 2 chains x 16 x 80B

__device__ __forceinline__ float sigf(float x) {
    float e = __builtin_amdgcn_exp2f(-x * K1);
    return __builtin_amdgcn_rcpf(1.0f + e);
}
__device__ __forceinline__ float logsigf(float x) {
    float ax = fabsf(x);
    float l = log1pf(__expf(-ax));
    return (x >= 0.0f) ? -l : x - l;
}
__device__ __forceinline__ bf16x8 loadu8(const float* __restrict__ p) {
    float4 a = ((const float4*)p)[0], b = ((const float4*)p)[1];
    bf16x8 r = { (__bf16)a.x, (__bf16)a.y, (__bf16)a.z, (__bf16)a.w,
                 (__bf16)b.x, (__bf16)b.y, (__bf16)b.z, (__bf16)b.w };
    return r;
}

// ---------------------------------------------------------------------------
// ids 0..16383           : weight images (bf16, Wu/Whh per hop)
// ids 16384..278527      : T  (2 hops x 32 j x 32 k x 128 g, f32)
// ids 278528..286719     : T0 (2 hops x 32 k x 128 g, f32)
__global__ __launch_bounds__(256)
void prep_tables(const float* __restrict__ ent, const float* __restrict__ rel,
                 const float* __restrict__ wih0, const float* __restrict__ whh0,
                 const float* __restrict__ bih0, const float* __restrict__ bhh0,
                 const float* __restrict__ wih1, const float* __restrict__ whh1,
                 const float* __restrict__ bih1, const float* __restrict__ bhh1,
                 float* __restrict__ T0, float* __restrict__ T,
                 float* __restrict__ wimg)
{
    const int id = blockIdx.x * 256 + threadIdx.x;
    if (id < 16384) {                            // weight images
        const int hop  = id >> 13;
        const int rest = id & 8191;
        const int mat  = rest >> 12;             // 0 = Wu, 1 = Whh
        const int e    = rest & 4095;
        const int gate = e >> 5, d = e & 31;
        float v = mat ? (hop ? whh1 : whh0)[(size_t)gate * 32 + d]
                      : (hop ? wih1 : wih0)[(size_t)gate * 64 + d];
        __bf16* base = (__bf16*)((char*)wimg + hop * WIMG_BYTES + mat * 10240);
        base[gate * 40 + d] = (__bf16)v;
    } else if (id < 16384 + 262144) {            // combined table T
        const int idt = id - 16384;
        const int hop = idt >> 17;
        const int r   = idt & 131071;            // j*4096 + k*128 + g
        const int j   = r >> 12;
        const int k   = (r >> 7) & 31;
        const int g   = r & 127;
        const float* wih = hop ? wih1 : wih0;
        const float4* w4 = (const float4*)(wih + (size_t)g * 64);
        const float4* r4 = (const float4*)(rel + (size_t)j * 32);
        const float4* e4 = (const float4*)(ent + (size_t)k * 32);
        float a = hop ? bih1[g] + bhh1[g] : bih0[g] + bhh0[g];
        #pragma unroll
        for (int i = 0; i < 8; ++i) {
            float4 w = w4[i], x = r4[i];
            a = fmaf(w.x, x.x, a); a = fmaf(w.y, x.y, a);
            a = fmaf(w.z, x.z, a); a = fmaf(w.w, x.w, a);
        }
        #pragma unroll
        for (int i = 0; i < 8; ++i) {
            float4 w = w4[8 + i], x = e4[i];
            a = fmaf(w.x, x.x, a); a = fmaf(w.y, x.y, a);
            a = fmaf(w.z, x.z, a); a = fmaf(w.w, x.w, a);
        }
        T[(size_t)hop * 131072 + r] = a;
    } else if (id < 16384 + 262144 + 8192) {     // step-0 table T0
        const int idb = id - 16384 - 262144;
        const int hop = idb >> 12;
        const int k   = (idb >> 7) & 31;
        const int g   = idb & 127;
        const float* wih = hop ? wih1 : wih0;
        const float4* w4 = (const float4*)(wih + (size_t)g * 64);
        const float4* e4 = (const float4*)(ent + (size_t)k * 32);
        float a = hop ? bih1[g] + bhh1[g] : bih0[g] + bhh0[g];
        #pragma unroll
        for (int i = 0; i < 8; ++i) {
            float4 w = w4[8 + i], x = e4[i];
            a = fmaf(w.x, x.x, a); a = fmaf(w.y, x.y, a);
            a = fmaf(w.z, x.z, a); a = fmaf(w.w, x.w, a);
        }
        T0[(size_t)hop * 4096 + k * 128 + g] = a;
    }
}

// nonlin in C-layout D[gate][pair] (verified R10): lane (q=lane>>4, p=lane&15),
// tile mt holds gates 16mt+4q+r of pair p -> unit quartets hf=0: 4q+r,
// hf=1: 16+4q+r. 4 exp2 + 2 rcp + 1 exp2 per unit.
template<bool FIRST, bool LAST>
__device__ __forceinline__ void nonlin(
    floatx4* __restrict__ acc, float* __restrict__ cst,
    float* __restrict__ hlo, float* __restrict__ hhi,
    char* __restrict__ Hw, int q, int bnl)
{
    #pragma unroll
    for (int hf = 0; hf < 2; ++hf) {
        float* hout = hf ? hhi : hlo;
        #pragma unroll
        for (int r = 0; r < 4; ++r) {
            float gi = acc[0 + hf][r], gf = acc[2 + hf][r],
                  gg = acc[4 + hf][r], go = acc[6 + hf][r];
            float Ai = 1.0f + __builtin_amdgcn_exp2f(-gi * K1);
            float Af = 1.0f + __builtin_amdgcn_exp2f(-gf * K1);
            float G2 = __builtin_amdgcn_exp2f(gg * K2);
            float Gp = G2 + 1.0f, Gm = G2 - 1.0f;
            float cold = FIRST ? 0.0f : cst[hf * 4 + r];
            float num = cold * Ai * Gp + Gm * Af;
            float c = num * __builtin_amdgcn_rcpf(Af * Ai * Gp);
            cst[hf * 4 + r] = c;
            float Ao = 1.0f + __builtin_amdgcn_exp2f(-go * K1);
            float C2 = __builtin_amdgcn_exp2f(c * K2);
            hout[r] = (C2 - 1.0f) * __builtin_amdgcn_rcpf(Ao * (C2 + 1.0f));
        }
    }
    if (!LAST) {
        bf16x4 plo = { (__bf16)hlo[0], (__bf16)hlo[1], (__bf16)hlo[2], (__bf16)hlo[3] };
        bf16x4 phi = { (__bf16)hhi[0], (__bf16)hhi[1], (__bf16)hhi[2], (__bf16)hhi[3] };
        *(bf16x4*)(Hw + bnl * 80 + 8 * q)      = plo;
        *(bf16x4*)(Hw + bnl * 80 + 32 + 8 * q) = phi;
    }
}

// Grid 4096: hop = bid&1, idx = bid>>1. 4 waves x 2 chains (batches idx*8+w,
// +4). Per chain-step: acc-init = 16 global dwordx4 from combined T (L2-hot),
// 8 MFMA (Whh@h or Wu@u), trans chain, h via wave-private LDS. One barrier.
__global__ __launch_bounds__(256, 3)
void hop_mfma(const float* __restrict__ user_table,
              const int*   __restrict__ users,
              const int*   __restrict__ items,
              const int*   __restrict__ lp0,     // (NE,P,3)
              const int*   __restrict__ lp1,     // (NE,P,5)
              const float* __restrict__ wimg,
              const float* __restrict__ T0g,
              const float* __restrict__ Tg,
              float* __restrict__ F0,            // (B,32) sum_p h
              float* __restrict__ F1)
{
    __shared__ __align__(16) char lds[LDS_BYTES];

    const bool second = blockIdx.x & 1;
    const int  idx    = blockIdx.x >> 1;
    const int tid  = threadIdx.x;
    const int lane = tid & 63;
    const int wave = tid >> 6;
    const int q    = lane >> 4;
    const int bnl  = lane & 15;

    // ---- weight image -> LDS (20480 B = 1280 float4, exactly 5 per thread) --
    {
        const float4* g4 = (const float4*)((const char*)wimg +
                                           (second ? WIMG_BYTES : 0));
        float4* l4 = (float4*)lds;
        #pragma unroll
        for (int i = 0; i < 5; ++i) l4[i * 256 + tid] = g4[i * 256 + tid];
    }

    const char* Wu  = lds + WU_OFF;
    const char* Whh = lds + WHH_OFF;
    char* HwA = lds + H_OFF + (wave * 2 + 0) * 1280;
    char* HwB = lds + H_OFF + (wave * 2 + 1) * 1280;

    // ---- per-chain setup ---------------------------------------------------
    const int fbA = idx * 8 + wave;
    const int fbB = fbA + 4;
    const int L   = second ? 5 : 3;
    const int* lp = second ? lp1 : lp0;
    const int* __restrict__ ilA = lp + ((size_t)items[fbA] * PP + bnl) * L;
    const int* __restrict__ ilB = lp + ((size_t)items[fbB] * PP + bnl) * L;
    int sqA[5], sqB[5];
    #pragma unroll
    for (int i = 0; i < 5; ++i) {
        sqA[i] = (i < L) ? ilA[i] : 0;
        sqB[i] = (i < L) ? ilB[i] : 0;
    }

    bf16x8 buA = loadu8(user_table + (size_t)users[fbA] * D + q * 8);
    bf16x8 buB = loadu8(user_table + (size_t)users[fbB] * D + q * 8);

    const float* T0h = T0g + (second ? 4096 : 0);
    const float* Th  = Tg  + (second ? 131072 : 0);

    __syncthreads();   // image ready

    float cstA[8], cstB[8], hloA[4], hhiA[4], hloB[4], hhiB[4];

    // ---- step 0: acc = T0[seed] ; += Wu @ u --------------------------------
    {
        const float* tA = T0h + sqA[0] * 128 + 4 * q;
        const float* tB = T0h + sqB[0] * 128 + 4 * q;
        floatx4 accA[8], accB[8];
        #pragma unroll
        for (int mt = 0; mt < 8; ++mt) {
            accA[mt] = *(const floatx4*)(tA + 16 * mt);
            accB[mt] = *(const floatx4*)(tB + 16 * mt);
        }
        #pragma unroll
        for (int mt = 0; mt < 8; ++mt) {
            bf16x8 wu = *(const bf16x8*)(Wu + (16 * mt + bnl) * 80 + q * 16);
            accA[mt] = __builtin_amdgcn_mfma_f32_16x16x32_bf16(wu, buA, accA[mt], 0, 0, 0);
            accB[mt] = __builtin_amdgcn_mfma_f32_16x16x32_bf16(wu, buB, accB[mt], 0, 0, 0);
        }
        nonlin<true, false>(accA, cstA, hloA, hhiA, HwA, q, bnl);
        nonlin<true, false>(accB, cstB, hloB, hhiB, HwB, q, bnl);
    }

    // ---- steps 1..T-1: acc = T[j][k] ; += Whh @ h --------------------------
    #pragma unroll
    for (int t = 1; t < 3; ++t) {
        if (t == 2 && !second) break;
        const bool last = (t == (second ? 2 : 1));
        const float* tA = Th + (((sqA[2 * t - 1]) << 5) + sqA[2 * t]) * 128 + 4 * q;
        const float* tB = Th + (((sqB[2 * t - 1]) << 5) + sqB[2 * t]) * 128 + 4 * q;
        floatx4 accA[8], accB[8];
        #pragma unroll
        for (int mt = 0; mt < 8; ++mt) {
            accA[mt] = *(const floatx4*)(tA + 16 * mt);
            accB[mt] = *(const floatx4*)(tB + 16 * mt);
        }
        bf16x8 bhA = *(const bf16x8*)(HwA + bnl * 80 + q * 16);
        bf16x8 bhB = *(const bf16x8*)(HwB + bnl * 80 + q * 16);
        #pragma unroll
        for (int mt = 0; mt < 8; ++mt) {
            bf16x8 wh = *(const bf16x8*)(Whh + (16 * mt + bnl) * 80 + q * 16);
            accA[mt] = __builtin_amdgcn_mfma_f32_16x16x32_bf16(wh, bhA, accA[mt], 0, 0, 0);
            accB[mt] = __builtin_amdgcn_mfma_f32_16x16x32_bf16(wh, bhB, accB[mt], 0, 0, 0);
        }
        if (last) {
            nonlin<false, true>(accA, cstA, hloA, hhiA, HwA, q, bnl);
            nonlin<false, true>(accB, cstB, hloB, hhiB, HwB, q, bnl);
        } else {
            nonlin<false, false>(accA, cstA, hloA, hhiA, HwA, q, bnl);
            nonlin<false, false>(accB, cstB, hloB, hhiB, HwB, q, bnl);
        }
    }

    // ---- sum over pairs (reduce across bnl lanes), write F -----------------
    #pragma unroll
    for (int r = 0; r < 4; ++r) {
        #pragma unroll
        for (int m = 1; m < 16; m <<= 1) {
            hloA[r] += __shfl_xor(hloA[r], m);
            hhiA[r] += __shfl_xor(hhiA[r], m);
            hloB[r] += __shfl_xor(hloB[r], m);
            hhiB[r] += __shfl_xor(hhiB[r], m);
        }
    }
    if (bnl == 0) {
        float* Fout = (second ? F1 : F0);
        float4 vloA = { hloA[0], hloA[1], hloA[2], hloA[3] };
        float4 vhiA = { hhiA[0], hhiA[1], hhiA[2], hhiA[3] };
        float4 vloB = { hloB[0], hloB[1], hloB[2], hloB[3] };
        float4 vhiB = { hhiB[0], hhiB[1], hhiB[2], hhiB[3] };
        *(float4*)(Fout + (size_t)fbA * D + 4 * q)      = vloA;
        *(float4*)(Fout + (size_t)fbA * D + 16 + 4 * q) = vhiA;
        *(float4*)(Fout + (size_t)fbB * D + 4 * q)      = vloB;
        *(float4*)(Fout + (size_t)fbB * D + 16 + 4 * q) = vhiB;
    }
}

// Per b: emb0=(ent[items]+F0)@W^T+b ; emb1=(emb0+F1)@W^T+b ; score=dot(u,emb1)
__global__ __launch_bounds__(256)
void chain_score(const float* __restrict__ user_table,
                 const float* __restrict__ ent_table,
                 const float* __restrict__ agg_w,
                 const float* __restrict__ agg_b,
                 const int*   __restrict__ users,
                 const int*   __restrict__ items,
                 const int*   __restrict__ ratings,
                 const float* __restrict__ F0,
                 const float* __restrict__ F1,
                 float* __restrict__ out,
                 float* __restrict__ partials)
{
    __shared__ float s[8][33];
    __shared__ float red[8];
    const int tid = threadIdx.x;
    const int bb  = tid >> 5;
    const int j   = tid & 31;
    const int b   = blockIdx.x * 8 + bb;
    const int it  = items[b];

    s[bb][j] = ent_table[(size_t)it * D + j] + F0[(size_t)b * D + j];
    __syncthreads();
    const float* __restrict__ w = agg_w + (size_t)j * D;
    float e0 = agg_b[j];
    #pragma unroll
    for (int k = 0; k < D; ++k) e0 = fmaf(s[bb][k], w[k], e0);
    __syncthreads();
    s[bb][j] = e0 + F1[(size_t)b * D + j];
    __syncthreads();
    float e1 = agg_b[j];
    #pragma unroll
    for (int k = 0; k < D; ++k) e1 = fmaf(s[bb][k], w[k], e1);

    float prod = user_table[(size_t)users[b] * D + j] * e1;
    #pragma unroll
    for (int m = 1; m < 32; m <<= 1) prod += __shfl_xor(prod, m);
    if (j == 0) {
        out[1 + b]      = sigf(prod);
        out[1 + BN + b] = (float)it;
        float r = (float)ratings[b];
        red[bb] = r * logsigf(prod) + (1.0f - r) * logsigf(-prod);
    }
    __syncthreads();
    if (tid == 0) {
        float t = 0.0f;
        #pragma unroll
        for (int qq = 0; qq < 8; ++qq) t += red[qq];
        partials[blockIdx.x] = t;
    }
}

__global__ __launch_bounds__(256)
void loss_kernel(const float* __restrict__ partials, float* __restrict__ out)
{
    __shared__ float red[4];
    const int t = threadIdx.x;
    float v = 0.0f;
    #pragma unroll
    for (int qq = 0; qq < 8; ++qq) v += partials[qq * 256 + t];
    #pragma unroll
    for (int m = 1; m < 64; m <<= 1) v += __shfl_xor(v, m);
    if ((t & 63) == 0) red[t >> 6] = v;
    __syncthreads();
    if (t == 0) out[0] = -(red[0] + red[1] + red[2] + red[3]) / (float)BN;
}

extern "C" void kernel_launch(void* const* d_in, const int* in_sizes, int n_in,
                              void* d_out, int out_size, void* d_ws, size_t ws_size,
                              hipStream_t stream)
{
    const float* user_table = (const float*)d_in[0];
    const float* ent_table  = (const float*)d_in[1];
    const float* rel_table  = (const float*)d_in[2];
    const float* w_ih0 = (const float*)d_in[3];
    const float* w_hh0 = (const float*)d_in[4];
    const float* b_ih0 = (const float*)d_in[5];
    const float* b_hh0 = (const float*)d_in[6];
    const float* w_ih1 = (const float*)d_in[7];
    const float* w_hh1 = (const float*)d_in[8];
    const float* b_ih1 = (const float*)d_in[9];
    const float* b_hh1 = (const float*)d_in[10];
    const float* agg_w = (const float*)d_in[11];
    const float* agg_b = (const float*)d_in[12];
    const int* users   = (const int*)d_in[13];
    const int* items   = (const int*)d_in[14];
    const int* ratings = (const int*)d_in[15];
    const int* lp0     = (const int*)d_in[16];
    const int* lp1     = (const int*)d_in[17];
    float* out = (float*)d_out;

    float* ws       = (float*)d_ws;
    float* F0       = ws;                              // BN*32
    float* F1       = F0 + (size_t)BN * D;             // BN*32
    float* partials = F1 + (size_t)BN * D;             // 2048
    float* T0       = partials + 2048;                 // 2*32*128   = 8192
    float* T        = T0 + 8192;                       // 2*1024*128 = 262144
    float* wimg     = T + 262144;                      // 2*WIMG_BYTES bytes

    prep_tables<<<1120, 256, 0, stream>>>(ent_table, rel_table,
        w_ih0, w_hh0, b_ih0, b_hh0, w_ih1, w_hh1, b_ih1, b_hh1, T0, T, wimg);
    hop_mfma<<<4096, 256, 0, stream>>>(
        user_table, users, items, lp0, lp1, wimg, T0, T, F0, F1);
    chain_score<<<BN / 8, 256, 0, stream>>>(
        user_table, ent_table, agg_w, agg_b, users, items, ratings,
        F0, F1, out, partials);
    loss_kernel<<<1, 256, 0, stream>>>(partials, out);
}